// Round 1
// baseline (421.238 us; speedup 1.0000x reference)
//
#include <hip/hip_runtime.h>
#include <stdint.h>

typedef unsigned short u16;
typedef unsigned int   u32;
typedef __attribute__((ext_vector_type(8))) __bf16 bf16x8;
typedef __attribute__((ext_vector_type(4))) float  f32x4;

#define MFMA_16x16x32_BF16(a, b, c) __builtin_amdgcn_mfma_f32_16x16x32_bf16((a), (b), (c), 0, 0, 0)

__device__ __forceinline__ u16 f2b(float f) {
    u32 u = __builtin_bit_cast(u32, f);
    u32 r = (u + 0x7FFFu + ((u >> 16) & 1u)) >> 16;
    return (u16)r;
}
__device__ __forceinline__ float b2f(u16 h) {
    u32 u = ((u32)h) << 16;
    return __builtin_bit_cast(float, u);
}

// async 16B/lane global->LDS. LDS dest is wave-uniform base + lane*16.
__device__ __forceinline__ void gload_lds16(const void* g, void* l) {
    __builtin_amdgcn_global_load_lds(
        (const __attribute__((address_space(1))) u32*)g,
        (__attribute__((address_space(3))) u32*)l,
        16, 0, 0);
}

// ---------------------------------------------------------------------------
// cast fp32 -> bf16 for x (8388608), w_qkv (12582912), w_proj (4194304)
// ---------------------------------------------------------------------------
__global__ __launch_bounds__(256) void cast3(const float* __restrict__ x,
                                             const float* __restrict__ wq,
                                             const float* __restrict__ wp,
                                             u16* __restrict__ xb,
                                             u16* __restrict__ wqb,
                                             u16* __restrict__ wpb) {
    const int n1 = 8388608, n2 = 12582912, n3 = 4194304;
    const int total4 = (n1 + n2 + n3) / 4;
    for (int i = blockIdx.x * blockDim.x + threadIdx.x; i < total4;
         i += gridDim.x * blockDim.x) {
        int e = i * 4;
        const float* src; u16* dst; int off;
        if (e < n1)            { src = x;  dst = xb;  off = e; }
        else if (e < n1 + n2)  { src = wq; dst = wqb; off = e - n1; }
        else                   { src = wp; dst = wpb; off = e - n1 - n2; }
        float4 v = *(const float4*)(src + off);
        ushort4 o;
        o.x = f2b(v.x); o.y = f2b(v.y); o.z = f2b(v.z); o.w = f2b(v.w);
        *(ushort4*)(dst + off) = o;
    }
}

// ---------------------------------------------------------------------------
// Legacy 128x128 GEMM (kept for the projection GEMM, N=2048 -> 512 blocks).
// ---------------------------------------------------------------------------
template <int OUT_BF16>
__global__ __launch_bounds__(256) void gemm_bt(const u16* __restrict__ A,
                                               const u16* __restrict__ Bt,
                                               void* __restrict__ Cout,
                                               int M, int N, int K) {
    __shared__ u16 Al[128 * 64];
    __shared__ u16 Bl[128 * 64];
    const int tid  = threadIdx.x;
    const int w    = tid >> 6;
    const int lane = tid & 63;
    const int quad = lane >> 4;
    const int l16  = lane & 15;
    const int m0 = blockIdx.y * 128;
    const int n0 = blockIdx.x * 128;
    const int wm = (w >> 1) * 64;
    const int wn = (w & 1) * 64;

    f32x4 acc[4][4];
#pragma unroll
    for (int i = 0; i < 4; i++) {
#pragma unroll
        for (int j = 0; j < 4; j++) acc[i][j] = (f32x4){0.f, 0.f, 0.f, 0.f};
    }

    const int srow = tid >> 3;
    const int scol = ((tid & 7) ^ (srow & 7)) * 8;
    const u16* Abase = A + (size_t)(m0 + srow) * K + scol;
    const u16* Bbase = Bt + (size_t)(n0 + srow) * K + scol;
    char* AlB = (char*)Al + w * 1024;
    char* BlB = (char*)Bl + w * 1024;
    const int fx = (l16 & 7);

    for (int k0 = 0; k0 < K; k0 += 64) {
        __syncthreads();
#pragma unroll
        for (int i = 0; i < 4; i++) {
            gload_lds16(Abase + (size_t)i * 32 * K + k0, AlB + i * 4096);
            gload_lds16(Bbase + (size_t)i * 32 * K + k0, BlB + i * 4096);
        }
        __syncthreads();
#pragma unroll
        for (int ks = 0; ks < 2; ks++) {
            const int cb = ((ks * 4 + quad) ^ fx) * 8;
            bf16x8 Af[4];
#pragma unroll
            for (int mi = 0; mi < 4; mi++)
                Af[mi] = *(const bf16x8*)&Al[(wm + mi * 16 + l16) * 64 + cb];
#pragma unroll
            for (int ni = 0; ni < 4; ni++) {
                bf16x8 Bf = *(const bf16x8*)&Bl[(wn + ni * 16 + l16) * 64 + cb];
#pragma unroll
                for (int mi = 0; mi < 4; mi++)
                    acc[mi][ni] = MFMA_16x16x32_BF16(Af[mi], Bf, acc[mi][ni]);
            }
        }
    }

    const int row0 = m0 + wm + quad * 4;
    const int col0 = n0 + wn + l16;
#pragma unroll
    for (int mi = 0; mi < 4; mi++) {
#pragma unroll
        for (int r = 0; r < 4; r++) {
            size_t rowb = (size_t)(row0 + mi * 16 + r) * N;
#pragma unroll
            for (int ni = 0; ni < 4; ni++) {
                float v = acc[mi][ni][r];
                if (OUT_BF16) ((u16*)Cout)[rowb + col0 + ni * 16] = f2b(v);
                else          ((float*)Cout)[rowb + col0 + ni * 16] = v;
            }
        }
    }
}

// ---------------------------------------------------------------------------
// 256x256 8-wave 4-phase-per-K-tile GEMM (T3+T4+T5 schedule, plain HIP).
// C[M,N] = A[M,K] * Bt[N,K]^T, bf16 in / fp32 acc.
//
// Geometry: BM=BN=256, BK=64, 512 thr = 8 waves (2M x 4N), per-wave 128x64.
// LDS 128 KiB dynamic: A and B, 2 dbuf, each tile as two K-half regions
// (256 rows x 32 cols = 16 KiB contiguous). Within a region, 16B block
// (row, kb) lives at slot (row>>3)*32 + kb*8 + (row&7): frag ds_read_b128
// (16 lanes, fixed kb) spreads over all 8 16B-slots of a 128B line -> 2-way
// (free). Staging source is inverse-permuted per-lane; LDS dest linear.
//
// Phase q of tile t (kk=q>>1, mh=q&1): read A-frags(mh) [+B-frags at q even],
// stage ONE 16 KiB unit of tile t+1 (2 gload_lds/thread), 16 MFMA in
// setprio(1). Stage order: q0->A.kh0, q1->B.kh0, q2->A.kh1, q3->B.kh1.
// vmcnt(4) at q0/q2 only (boundary + K-half boundary): waits exactly the two
// units this half-tile reads, leaves the 4 newest loads in flight -> the
// staging queue NEVER drains in the main loop. Every unit has 4 phases
// (~1000 cyc) of issue->use slack. Writes target the buffer whose reads
// completed a full tile earlier -> barrier-proven safe (no timing reliance).
// ---------------------------------------------------------------------------
template <int OUT_BF16>
__global__ __launch_bounds__(512, 2) void gemm256(const u16* __restrict__ A,
                                                  const u16* __restrict__ Bt,
                                                  void* __restrict__ Cout,
                                                  int N, int K, int nbx) {
    extern __shared__ char smem[];
    const int tid  = threadIdx.x;
    const int w    = tid >> 6;
    const int lane = tid & 63;
    const int quad = lane >> 4;
    const int l16  = lane & 15;

    // XCD-aware swizzle (gridDim.x % 8 == 0)
    const int nwg = gridDim.x;
    const int cpx = nwg >> 3;
    const int bid = blockIdx.x;
    const int swz = (bid & 7) * cpx + (bid >> 3);
    const int bx  = swz % nbx;
    const int by  = swz / nbx;
    const int m0 = by * 256, n0 = bx * 256;
    const int wr = w >> 2, wc = w & 3;

    // fragment-read per-lane byte offset within a K-half region
    const int loff = (((l16 >> 3) * 32) + quad * 8 + (l16 & 7)) * 16;

    // staging: LDS slot s = i*512 + tid holds global (row=(s>>5)*8+(s&7), kb=(s>>3)&3)
    const int rowS = ((tid >> 5) * 8) + (tid & 7);
    const int kbS  = (tid >> 3) & 3;
    const u16* Asrc = A  + (size_t)(m0 + rowS) * K + kbS * 8;
    const u16* Bsrc = Bt + (size_t)(n0 + rowS) * K + kbS * 8;
    char* const smA = smem;            // A: [buf][kh] 4 x 16 KiB
    char* const smB = smem + 65536;    // B: same
    const int woff = w * 1024;

    f32x4 acc[8][4];
#pragma unroll
    for (int i = 0; i < 8; i++)
#pragma unroll
        for (int j = 0; j < 4; j++) acc[i][j] = (f32x4){0.f, 0.f, 0.f, 0.f};

    const int NT = K >> 6;

#define STAGE_UNIT(t_, kh_, isB_)                                              \
    {                                                                          \
        const u16* s_ = (isB_ ? Bsrc : Asrc) + (size_t)(t_)*64 + (kh_)*32;     \
        char* d_ = (isB_ ? smB : smA) + ((t_)&1) * 32768 + (kh_)*16384 + woff; \
        gload_lds16(s_, d_);                                                   \
        gload_lds16(s_ + (size_t)128 * K, d_ + 8192);                          \
    }

#define LOAD_A(KH, MH)                                                         \
    {                                                                          \
        const char* Ab_ = smA + bufo + (KH)*16384 + (wr * 128 + (MH)*64) * 64; \
        _Pragma("unroll")                                                      \
        for (int mi = 0; mi < 4; mi++)                                         \
            Af[mi] = *(const bf16x8*)(Ab_ + mi * 1024 + loff);                 \
    }

#define LOAD_B(KH)                                                             \
    {                                                                          \
        const char* Bb_ = smB + bufo + (KH)*16384 + (wc * 64) * 64;            \
        _Pragma("unroll")                                                      \
        for (int ni = 0; ni < 4; ni++)                                         \
            Bf[ni] = *(const bf16x8*)(Bb_ + ni * 1024 + loff);                 \
    }

#define MFMA_PHASE(MB)                                                         \
    __builtin_amdgcn_s_setprio(1);                                             \
    _Pragma("unroll")                                                          \
    for (int ni = 0; ni < 4; ni++) {                                           \
        _Pragma("unroll")                                                      \
        for (int mi = 0; mi < 4; mi++)                                         \
            acc[(MB) + mi][ni] =                                               \
                MFMA_16x16x32_BF16(Af[mi], Bf[ni], acc[(MB) + mi][ni]);        \
    }                                                                          \
    __builtin_amdgcn_s_setprio(0);                                             \
    __builtin_amdgcn_sched_barrier(0);

    // prologue: stage all 4 units of tile 0 (8 loads in flight)
    STAGE_UNIT(0, 0, 0);
    STAGE_UNIT(0, 0, 1);
    STAGE_UNIT(0, 1, 0);
    STAGE_UNIT(0, 1, 1);

    for (int t = 0; t < NT; ++t) {
        const int bufo = (t & 1) * 32768;
        const int pf = (t + 1 < NT);
        bf16x8 Af[4], Bf[4];

        // ---- phase 0: kk=0, mh=0 ----
        asm volatile("s_waitcnt vmcnt(4)" ::: "memory");
        __builtin_amdgcn_s_barrier();
        LOAD_A(0, 0);
        LOAD_B(0);
        if (pf) STAGE_UNIT(t + 1, 0, 0);
        MFMA_PHASE(0);

        // ---- phase 1: kk=0, mh=1 ----
        __builtin_amdgcn_s_barrier();
        LOAD_A(0, 1);
        if (pf) STAGE_UNIT(t + 1, 0, 1);
        MFMA_PHASE(4);

        // ---- phase 2: kk=1, mh=0 ----
        if (pf) { asm volatile("s_waitcnt vmcnt(4)" ::: "memory"); }
        else    { asm volatile("s_waitcnt vmcnt(0)" ::: "memory"); }
        __builtin_amdgcn_s_barrier();
        LOAD_A(1, 0);
        LOAD_B(1);
        if (pf) STAGE_UNIT(t + 1, 1, 0);
        MFMA_PHASE(0);

        // ---- phase 3: kk=1, mh=1 ----
        __builtin_amdgcn_s_barrier();
        LOAD_A(1, 1);
        if (pf) STAGE_UNIT(t + 1, 1, 1);
        MFMA_PHASE(4);
    }

#undef STAGE_UNIT
#undef LOAD_A
#undef LOAD_B
#undef MFMA_PHASE

    // epilogue: acc[mf][ni] -> C[m0 + wr*128 + mf*16 + quad*4 + r][n0 + wc*64 + ni*16 + l16]
    const int row0 = m0 + wr * 128 + quad * 4;
    const int col0 = n0 + wc * 64 + l16;
#pragma unroll
    for (int mf = 0; mf < 8; mf++) {
#pragma unroll
        for (int r = 0; r < 4; r++) {
            size_t rowb = (size_t)(row0 + mf * 16 + r) * N;
#pragma unroll
            for (int ni = 0; ni < 4; ni++) {
                float v = acc[mf][ni][r];
                if (OUT_BF16) ((u16*)Cout)[rowb + col0 + ni * 16] = f2b(v);
                else          ((float*)Cout)[rowb + col0 + ni * 16] = v;
            }
        }
    }
}

// ---------------------------------------------------------------------------
// RoPE(q,k): qkv[B,T,3,H,Dh] -> Q,K (roped) in [B,H,T,Dh]. block per (b,t).
// ---------------------------------------------------------------------------
__global__ __launch_bounds__(256) void rope_qk(const u16* __restrict__ qkv,
                                               u16* __restrict__ Q,
                                               u16* __restrict__ K) {
    const int bt = blockIdx.x;          // 0..4095
    const int b = bt >> 11, t = bt & 2047;
    const u16* row = qkv + (size_t)bt * 6144;
    const int tid = threadIdx.x;

#pragma unroll
    for (int it = 0; it < 8; it++) {
        int p   = it * 256 + tid;
        int qk  = p >> 10;          // 0=q, 1=k (uniform per it)
        int rem = p & 1023;
        int h   = rem >> 6;
        int i   = rem & 63;
        float x1 = b2f(row[qk * 2048 + h * 128 + i]);
        float x2 = b2f(row[qk * 2048 + h * 128 + i + 64]);
        float inv = expf(-0.14391156f * (float)i);   // 10000^(-i/64)
        float th  = (float)t * inv;
        float s, c;
        sincosf(th, &s, &c);
        float o1 = x1 * c - x2 * s;
        float o2 = x2 * c + x1 * s;
        u16* dst = (qk ? K : Q) + ((size_t)((b * 16 + h) * 2048 + t)) * 128;
        dst[i]      = f2b(o1);
        dst[i + 64] = f2b(o2);
    }
}

// ---------------------------------------------------------------------------
// V transpose: qkv[B,T,3,H,Dh] (v slice) -> VT[B,H,Dh,T]. grid (32 tc, 32 bh).
// ---------------------------------------------------------------------------
__global__ __launch_bounds__(256) void vtrans(const u16* __restrict__ qkv,
                                              u16* __restrict__ VT) {
    __shared__ u16 S[64 * 136];         // [t][d], stride 136
    const int tc = blockIdx.x;
    const int bh = blockIdx.y;
    const int b = bh >> 4, h = bh & 15;
    const int tid = threadIdx.x;

#pragma unroll
    for (int i = 0; i < 4; i++) {
        int idx = i * 256 + tid;
        int t  = idx >> 4;
        int d8 = (idx & 15) * 8;
        uint4 v = *(const uint4*)(qkv + ((size_t)(b * 2048 + tc * 64 + t)) * 6144
                                      + 4096 + h * 128 + d8);
        *(uint4*)&S[t * 136 + d8] = v;
    }
    __syncthreads();
#pragma unroll
    for (int i = 0; i < 4; i++) {
        int idx = i * 256 + tid;
        int d  = idx >> 3;
        int t8 = (idx & 7) * 8;
        u16 tmp[8];
#pragma unroll
        for (int j = 0; j < 8; j++) tmp[j] = S[(t8 + j) * 136 + d];
        *(uint4*)(VT + ((size_t)(bh * 128 + d)) * 2048 + tc * 64 + t8) = *(uint4*)tmp;
    }
}

// ---------------------------------------------------------------------------
// causal flash attention v4: v3 + XOR-swizzled K/V LDS tiles.
// grid (16 pairs, 32 bh), 256 thr. Block = 64 q-rows; wave = 16 q-rows.
// ---------------------------------------------------------------------------
__global__ __launch_bounds__(256) void attn(const u16* __restrict__ Q,
                                            const u16* __restrict__ Kg,
                                            const u16* __restrict__ VTg,
                                            u16* __restrict__ O) {
    __shared__ u16 Kl[2][64 * 128];     // [buf][key][d], swizzled
    __shared__ u16 Vt[2][128 * 64];     // [buf][d][key], swizzled
    __shared__ u16 Pl[4 * 16 * 76];     // per-wave P[q][key], stride 76

    const int tid  = threadIdx.x;
    const int w    = tid >> 6;
    const int lane = tid & 63;
    const int quad = lane >> 4;
    const int l16  = lane & 15;
    const int pair = blockIdx.x;        // 0..15
    const int bh   = blockIdx.y;        // 0..31
    const int b = bh >> 4, h = bh & 15;
    const size_t base = (size_t)bh * 2048 * 128;
    const u16* Qb  = Q + base;
    const u16* Kb  = Kg + base;
    const u16* VTb = VTg + base;        // [128 d][2048 t]
    u16* Plw = Pl + w * 16 * 76;
    const float scale = 0.08838834764831845f;   // 1/sqrt(128)

    const int krow = tid >> 4;
    const int kcol = (((tid & 15) ^ (krow & 7)) * 8);
    const int vrow = w * 8 + (lane >> 3);
    const int vcol = (((lane & 7) ^ (vrow & 7)) * 8);
    const int fx   = (l16 & 7);

    for (int s = 0; s < 2; s++) {
        const int qt   = s ? (31 - pair) : pair;
        const int q0   = qt * 64;
        const int row0 = q0 + w * 16;

        bf16x8 Qf[4];
#pragma unroll
        for (int kk = 0; kk < 4; kk++)
            Qf[kk] = *(const bf16x8*)&Qb[(size_t)(row0 + l16) * 128 + kk * 32 + quad * 8];

        f32x4 Oacc[8];
#pragma unroll
        for (int ni = 0; ni < 8; ni++) Oacc[ni] = (f32x4){0.f, 0.f, 0.f, 0.f};
        float mrow = -1e30f, lrow = 0.f;

        const int nkt = qt + 1;

        __syncthreads();
        {
            const u16* ksrc = Kb + (size_t)krow * 128 + kcol;
            char* kdst = (char*)Kl[0] + w * 1024;
            const u16* vsrc = VTb + (size_t)vrow * 2048 + vcol;
            char* vdst = (char*)Vt[0] + w * 1024;
#pragma unroll
            for (int i = 0; i < 4; i++) {
                gload_lds16(ksrc + (size_t)i * 16 * 128, kdst + i * 4096);
                gload_lds16(vsrc + (size_t)i * 32 * 2048, vdst + i * 4096);
            }
        }

        for (int kt = 0; kt < nkt; kt++) {
            const int kt0 = kt * 64;
            const int cur = kt & 1;
            __syncthreads();

            if (kt + 1 < nkt) {
                const int kt1 = kt0 + 64;
                const u16* ksrc = Kb + (size_t)(kt1 + krow) * 128 + kcol;
                char* kdst = (char*)Kl[cur ^ 1] + w * 1024;
                const u16* vsrc = VTb + (size_t)vrow * 2048 + kt1 + vcol;
                char* vdst = (char*)Vt[cur ^ 1] + w * 1024;
#pragma unroll
                for (int i = 0; i < 4; i++) {
                    gload_lds16(ksrc + (size_t)i * 16 * 128, kdst + i * 4096);
                    gload_lds16(vsrc + (size_t)i * 32 * 2048, vdst + i * 4096);
                }
            }

            const u16* Klc = Kl[cur];
            const u16* Vtc = Vt[cur];

            f32x4 ST[4];
#pragma unroll
            for (int mi = 0; mi < 4; mi++) ST[mi] = (f32x4){0.f, 0.f, 0.f, 0.f};
#pragma unroll
            for (int kk = 0; kk < 4; kk++) {
                const int cb = ((kk * 4 + quad) ^ fx) * 8;
#pragma unroll
                for (int mi = 0; mi < 4; mi++) {
                    bf16x8 Kf = *(const bf16x8*)&Klc[(mi * 16 + l16) * 128 + cb];
                    ST[mi] = MFMA_16x16x32_BF16(Kf, Qf[kk], ST[mi]);
                }
            }

            const bool needs_mask = (kt0 + 63) > row0;
            const int qg = row0 + l16;
            float tmax = -1e30f;
#pragma unroll
            for (int mi = 0; mi < 4; mi++) {
#pragma unroll
                for (int r = 0; r < 4; r++) {
                    float sv = ST[mi][r] * scale;
                    if (needs_mask) {
                        int kg = kt0 + mi * 16 + quad * 4 + r;
                        sv = (kg > qg) ? -1e30f : sv;
                    }
                    ST[mi][r] = sv;
                    tmax = fmaxf(tmax, sv);
                }
            }
            tmax = fmaxf(tmax, __shfl_xor(tmax, 16));
            tmax = fmaxf(tmax, __shfl_xor(tmax, 32));

            float mnew  = fmaxf(mrow, tmax);
            float alpha = __expf(mrow - mnew);
            mrow = mnew;

            float tsum = 0.f;
#pragma unroll
            for (int mi = 0; mi < 4; mi++) {
#pragma unroll
                for (int r = 0; r < 4; r++) {
                    float p = __expf(ST[mi][r] - mnew);
                    ST[mi][r] = p;
                    tsum += p;
                }
            }
            lrow = lrow * alpha + tsum;

#pragma unroll
            for (int mi = 0; mi < 4; mi++) {
                ushort4 pk;
                pk.x = f2b(ST[mi][0]); pk.y = f2b(ST[mi][1]);
                pk.z = f2b(ST[mi][2]); pk.w = f2b(ST[mi][3]);
                *(ushort4*)&Plw[l16 * 76 + mi * 16 + quad * 4] = pk;
            }

            float aRow[4];
#pragma unroll
            for (int r = 0; r < 4; r++) aRow[r] = __shfl(alpha, quad * 4 + r);
#pragma unroll
            for (int ni = 0; ni < 8; ni++) {
#pragma unroll
                for (int r = 0; r < 4; r++) Oacc[ni][r] *= aRow[r];
            }

            bf16x8 Pf[2];
#pragma unroll
            for (int kk = 0; kk < 2; kk++)
                Pf[kk] = *(const bf16x8*)&Plw[l16 * 76 + kk * 32 + quad * 8];
#pragma unroll
            for (int kk = 0; kk < 2; kk++) {
                const int cb = ((kk * 4 + quad) ^ fx) * 8;
#pragma unroll
                for (int ni = 0; ni < 8; ni++) {
                    bf16x8 Vf = *(const bf16x8*)&Vtc[(ni * 16 + l16) * 64 + cb];
                    Oacc[ni] = MFMA_16x16x32_BF16(Pf[kk], Vf, Oacc[ni]);
                }
            }
        }

        lrow += __shfl_xor(lrow, 16);
        lrow += __shfl_xor(lrow, 32);
        float inv = 1.0f / lrow;
        float iRow[4];
#pragma unroll
        for (int r = 0; r < 4; r++) iRow[r] = __shfl(inv, quad * 4 + r);

#pragma unroll
        for (int r = 0; r < 4; r++) {
            int t = row0 + quad * 4 + r;
            size_t rowb = ((size_t)(b * 2048 + t)) * 2048 + (size_t)(h * 128);
#pragma unroll
            for (int ni = 0; ni < 8; ni++)
                O[rowb + ni * 16 + l16] = f2b(Oacc[ni][r] * iRow[r]);
        }
    }
}

// ---------------------------------------------------------------------------
extern "C" void kernel_launch(void* const* d_in, const int* in_sizes, int n_in,
                              void* d_out, int out_size, void* d_ws, size_t ws_size,
                              hipStream_t stream) {
    const float* x  = (const float*)d_in[0];
    const float* wq = (const float*)d_in[1];
    const float* wp = (const float*)d_in[2];

    char* ws = (char*)d_ws;
    u16* xb   = (u16*)(ws + 0);            // 16,777,216
    u16* wqb  = (u16*)(ws + 16777216);     // 25,165,824
    u16* wpb  = (u16*)(ws + 41943040);     //  8,388,608
    u16* qkvb = (u16*)(ws + 50331648);     // 50,331,648
    u16* Qr   = (u16*)(ws + 100663296);    // 16,777,216
    u16* Kr   = (u16*)(ws + 117440512);    // 16,777,216
    u16* VTt  = (u16*)(ws + 134217728);    // 16,777,216 (V^T, [B,H,Dh,T])
    u16* Ob   = (u16*)(ws + 50331648);     // overlays qkvb (free after rope/vtrans)
    if (ws_size < 150994944) return;

    // one-time: allow 128 KiB dynamic LDS for gemm256; fall back if refused
    static int use256 = -1;
    if (use256 < 0) {
        hipError_t e = hipFuncSetAttribute(
            reinterpret_cast<const void*>(&gemm256<1>),
            hipFuncAttributeMaxDynamicSharedMemorySize, 131072);
        use256 = (e == hipSuccess) ? 1 : 0;
    }

    cast3<<<2048, 256, 0, stream>>>(x, wq, wp, xb, wqb, wpb);
    if (use256) {
        // grid 384 = (6144/256) x (4096/256); %8==0 for XCD swizzle
        gemm256<1><<<384, 512, 131072, stream>>>(xb, wqb, qkvb, 6144, 2048, 24);
    } else {
        gemm_bt<1><<<dim3(48, 32), 256, 0, stream>>>(xb, wqb, qkvb, 4096, 6144, 2048);
    }
    rope_qk<<<4096, 256, 0, stream>>>(qkvb, Qr, Kr);
    vtrans<<<dim3(32, 32), 256, 0, stream>>>(qkvb, VTt);
    attn<<<dim3(16, 32), 256, 0, stream>>>(Qr, Kr, VTt, Ob);
    gemm_bt<0><<<dim3(16, 32), 256, 0, stream>>>(Ob, wpb, (float*)d_out, 4096, 2048, 2048);
}

// Round 2
// 417.624 us; speedup vs baseline: 1.0087x; 1.0087x over previous
//
#include <hip/hip_runtime.h>
#include <stdint.h>

typedef unsigned short u16;
typedef unsigned int   u32;
typedef __attribute__((ext_vector_type(8))) __bf16 bf16x8;
typedef __attribute__((ext_vector_type(4))) float  f32x4;

#define MFMA_16x16x32_BF16(a, b, c) __builtin_amdgcn_mfma_f32_16x16x32_bf16((a), (b), (c), 0, 0, 0)

__device__ __forceinline__ u16 f2b(float f) {
    u32 u = __builtin_bit_cast(u32, f);
    u32 r = (u + 0x7FFFu + ((u >> 16) & 1u)) >> 16;
    return (u16)r;
}
__device__ __forceinline__ float b2f(u16 h) {
    u32 u = ((u32)h) << 16;
    return __builtin_bit_cast(float, u);
}

// async 16B/lane global->LDS. LDS dest is wave-uniform base + lane*16.
__device__ __forceinline__ void gload_lds16(const void* g, void* l) {
    __builtin_amdgcn_global_load_lds(
        (const __attribute__((address_space(1))) u32*)g,
        (__attribute__((address_space(3))) u32*)l,
        16, 0, 0);
}

// ---------------------------------------------------------------------------
// cast fp32 -> bf16 for x (8388608), w_qkv (12582912), w_proj (4194304)
// ---------------------------------------------------------------------------
__global__ __launch_bounds__(256) void cast3(const float* __restrict__ x,
                                             const float* __restrict__ wq,
                                             const float* __restrict__ wp,
                                             u16* __restrict__ xb,
                                             u16* __restrict__ wqb,
                                             u16* __restrict__ wpb) {
    const int n1 = 8388608, n2 = 12582912, n3 = 4194304;
    const int total4 = (n1 + n2 + n3) / 4;
    for (int i = blockIdx.x * blockDim.x + threadIdx.x; i < total4;
         i += gridDim.x * blockDim.x) {
        int e = i * 4;
        const float* src; u16* dst; int off;
        if (e < n1)            { src = x;  dst = xb;  off = e; }
        else if (e < n1 + n2)  { src = wq; dst = wqb; off = e - n1; }
        else                   { src = wp; dst = wpb; off = e - n1 - n2; }
        float4 v = *(const float4*)(src + off);
        ushort4 o;
        o.x = f2b(v.x); o.y = f2b(v.y); o.z = f2b(v.z); o.w = f2b(v.w);
        *(ushort4*)(dst + off) = o;
    }
}

// ---------------------------------------------------------------------------
// Legacy 128x128 GEMM (kept for the projection GEMM, N=2048 -> 512 blocks).
// ---------------------------------------------------------------------------
template <int OUT_BF16>
__global__ __launch_bounds__(256) void gemm_bt(const u16* __restrict__ A,
                                               const u16* __restrict__ Bt,
                                               void* __restrict__ Cout,
                                               int M, int N, int K) {
    __shared__ u16 Al[128 * 64];
    __shared__ u16 Bl[128 * 64];
    const int tid  = threadIdx.x;
    const int w    = tid >> 6;
    const int lane = tid & 63;
    const int quad = lane >> 4;
    const int l16  = lane & 15;
    const int m0 = blockIdx.y * 128;
    const int n0 = blockIdx.x * 128;
    const int wm = (w >> 1) * 64;
    const int wn = (w & 1) * 64;

    f32x4 acc[4][4];
#pragma unroll
    for (int i = 0; i < 4; i++) {
#pragma unroll
        for (int j = 0; j < 4; j++) acc[i][j] = (f32x4){0.f, 0.f, 0.f, 0.f};
    }

    const int srow = tid >> 3;
    const int scol = ((tid & 7) ^ (srow & 7)) * 8;
    const u16* Abase = A + (size_t)(m0 + srow) * K + scol;
    const u16* Bbase = Bt + (size_t)(n0 + srow) * K + scol;
    char* AlB = (char*)Al + w * 1024;
    char* BlB = (char*)Bl + w * 1024;
    const int fx = (l16 & 7);

    for (int k0 = 0; k0 < K; k0 += 64) {
        __syncthreads();
#pragma unroll
        for (int i = 0; i < 4; i++) {
            gload_lds16(Abase + (size_t)i * 32 * K + k0, AlB + i * 4096);
            gload_lds16(Bbase + (size_t)i * 32 * K + k0, BlB + i * 4096);
        }
        __syncthreads();
#pragma unroll
        for (int ks = 0; ks < 2; ks++) {
            const int cb = ((ks * 4 + quad) ^ fx) * 8;
            bf16x8 Af[4];
#pragma unroll
            for (int mi = 0; mi < 4; mi++)
                Af[mi] = *(const bf16x8*)&Al[(wm + mi * 16 + l16) * 64 + cb];
#pragma unroll
            for (int ni = 0; ni < 4; ni++) {
                bf16x8 Bf = *(const bf16x8*)&Bl[(wn + ni * 16 + l16) * 64 + cb];
#pragma unroll
                for (int mi = 0; mi < 4; mi++)
                    acc[mi][ni] = MFMA_16x16x32_BF16(Af[mi], Bf, acc[mi][ni]);
            }
        }
    }

    const int row0 = m0 + wm + quad * 4;
    const int col0 = n0 + wn + l16;
#pragma unroll
    for (int mi = 0; mi < 4; mi++) {
#pragma unroll
        for (int r = 0; r < 4; r++) {
            size_t rowb = (size_t)(row0 + mi * 16 + r) * N;
#pragma unroll
            for (int ni = 0; ni < 4; ni++) {
                float v = acc[mi][ni][r];
                if (OUT_BF16) ((u16*)Cout)[rowb + col0 + ni * 16] = f2b(v);
                else          ((float*)Cout)[rowb + col0 + ni * 16] = v;
            }
        }
    }
}

// ---------------------------------------------------------------------------
// 256x256 8-wave GEMM, m201-style two-barrier 4-phase schedule (T2+T3+T4+T5).
// C[M,N] = A[M,K] * Bt[N,K]^T, bf16 in / fp32 acc.
//
// Geometry: BM=BN=256, BK=64, 512 thr = 8 waves (2M x 4N), per-wave 128x64.
// LDS 128 KiB dynamic: A,B x 2 dbuf; each tile = two K-half regions
// (256 rows x 32 cols = 16 KiB). Slot swizzle (row>>3)*32+kb*8+(row&7):
// frag ds_read_b128 conflict-free (measured 0), staging source per-lane
// pre-permuted, LDS dest linear (gload_lds requirement).
//
// Phase template (the round-1 fix): reads+stage issued BEFORE barrier A, so
// the LDS pipe services them while waves wait out MFMA stragglers in the
// barrier; then lgkmcnt(0) is cheap and MFMA starts immediately.
//   { ds_read frags ; stage 1 unit of tile t+1 ; sched_barrier ;
//     s_barrier(A) ; lgkmcnt(0) ; sched_barrier ;
//     setprio(1) 16xMFMA setprio(0) ; [vmcnt at q1/q3] ; s_barrier(B) }
// vmcnt(4) at tails of q1 (certifies kh1 units for q2/q3 reads) and q3
// (certifies next tile's kh0) -- in-flight stays 8/6, never drained to 0
// in the main loop. Last tile: q1 tail uses vmcnt(0) (only 4 in flight).
// ---------------------------------------------------------------------------
template <int OUT_BF16>
__global__ __launch_bounds__(512, 2) void gemm256(const u16* __restrict__ A,
                                                  const u16* __restrict__ Bt,
                                                  void* __restrict__ Cout,
                                                  int N, int K, int nbx) {
    extern __shared__ char smem[];
    const int tid  = threadIdx.x;
    const int w    = tid >> 6;
    const int lane = tid & 63;
    const int quad = lane >> 4;
    const int l16  = lane & 15;

    // XCD-aware swizzle (gridDim.x % 8 == 0)
    const int nwg = gridDim.x;
    const int cpx = nwg >> 3;
    const int bid = blockIdx.x;
    const int swz = (bid & 7) * cpx + (bid >> 3);
    const int bx  = swz % nbx;
    const int by  = swz / nbx;
    const int m0 = by * 256, n0 = bx * 256;
    const int wr = w >> 2, wc = w & 3;

    // fragment-read per-lane byte offset within a K-half region
    const int loff = (((l16 >> 3) * 32) + quad * 8 + (l16 & 7)) * 16;

    // staging: LDS slot s = i*512 + tid holds global (row=(s>>5)*8+(s&7), kb=(s>>3)&3)
    const int rowS = ((tid >> 5) * 8) + (tid & 7);
    const int kbS  = (tid >> 3) & 3;
    const u16* Asrc = A  + (size_t)(m0 + rowS) * K + kbS * 8;
    const u16* Bsrc = Bt + (size_t)(n0 + rowS) * K + kbS * 8;
    char* const smA = smem;            // A: [buf][kh] 4 x 16 KiB
    char* const smB = smem + 65536;    // B: same
    const int woff = w * 1024;

    f32x4 acc[8][4];
#pragma unroll
    for (int i = 0; i < 8; i++)
#pragma unroll
        for (int j = 0; j < 4; j++) acc[i][j] = (f32x4){0.f, 0.f, 0.f, 0.f};

    const int NT = K >> 6;

#define STAGE_UNIT(t_, kh_, isB_)                                              \
    {                                                                          \
        const u16* s_ = (isB_ ? Bsrc : Asrc) + (size_t)(t_)*64 + (kh_)*32;     \
        char* d_ = (isB_ ? smB : smA) + ((t_)&1) * 32768 + (kh_)*16384 + woff; \
        gload_lds16(s_, d_);                                                   \
        gload_lds16(s_ + (size_t)128 * K, d_ + 8192);                          \
    }

#define LOAD_A(KH, MH)                                                         \
    {                                                                          \
        const char* Ab_ = smA + bufo + (KH)*16384 + (wr * 128 + (MH)*64) * 64; \
        _Pragma("unroll")                                                      \
        for (int mi = 0; mi < 4; mi++)                                         \
            Af[mi] = *(const bf16x8*)(Ab_ + mi * 1024 + loff);                 \
    }

#define LOAD_B(KH)                                                             \
    {                                                                          \
        const char* Bb_ = smB + bufo + (KH)*16384 + (wc * 64) * 64;            \
        _Pragma("unroll")                                                      \
        for (int ni = 0; ni < 4; ni++)                                         \
            Bf[ni] = *(const bf16x8*)(Bb_ + ni * 1024 + loff);                 \
    }

#define BARRIER_A()                                                            \
    __builtin_amdgcn_sched_barrier(0);                                         \
    __builtin_amdgcn_s_barrier();                                              \
    asm volatile("s_waitcnt lgkmcnt(0)" ::: "memory");                         \
    __builtin_amdgcn_sched_barrier(0);

#define MFMA_PHASE(MB)                                                         \
    __builtin_amdgcn_s_setprio(1);                                             \
    _Pragma("unroll")                                                          \
    for (int ni = 0; ni < 4; ni++) {                                           \
        _Pragma("unroll")                                                      \
        for (int mi = 0; mi < 4; mi++)                                         \
            acc[(MB) + mi][ni] =                                               \
                MFMA_16x16x32_BF16(Af[mi], Bf[ni], acc[(MB) + mi][ni]);        \
    }                                                                          \
    __builtin_amdgcn_s_setprio(0);                                             \
    __builtin_amdgcn_sched_barrier(0);

    // prologue: stage all 4 units of tile 0 (8 loads in flight), certify kh0
    STAGE_UNIT(0, 0, 0);
    STAGE_UNIT(0, 0, 1);
    STAGE_UNIT(0, 1, 0);
    STAGE_UNIT(0, 1, 1);
    asm volatile("s_waitcnt vmcnt(4)" ::: "memory");
    __builtin_amdgcn_s_barrier();

    for (int t = 0; t < NT; ++t) {
        const int bufo = (t & 1) * 32768;
        const int pf = (t + 1 < NT);
        bf16x8 Af[4], Bf[4];

        // ---- phase 0: kh0, mh0 ----
        LOAD_A(0, 0);
        LOAD_B(0);
        if (pf) STAGE_UNIT(t + 1, 0, 0);
        BARRIER_A();
        MFMA_PHASE(0);
        __builtin_amdgcn_s_barrier();

        // ---- phase 1: kh0, mh1 ----
        LOAD_A(0, 1);
        if (pf) STAGE_UNIT(t + 1, 0, 1);
        BARRIER_A();
        MFMA_PHASE(4);
        if (pf) { asm volatile("s_waitcnt vmcnt(4)" ::: "memory"); }
        else    { asm volatile("s_waitcnt vmcnt(0)" ::: "memory"); }
        __builtin_amdgcn_s_barrier();   // certifies kh1 units for phases 2/3

        // ---- phase 2: kh1, mh0 ----
        LOAD_A(1, 0);
        LOAD_B(1);
        if (pf) STAGE_UNIT(t + 1, 1, 0);
        BARRIER_A();
        MFMA_PHASE(0);
        __builtin_amdgcn_s_barrier();

        // ---- phase 3: kh1, mh1 ----
        LOAD_A(1, 1);
        if (pf) STAGE_UNIT(t + 1, 1, 1);
        BARRIER_A();
        MFMA_PHASE(4);
        asm volatile("s_waitcnt vmcnt(4)" ::: "memory");  // next tile kh0 (no-op on last)
        __builtin_amdgcn_s_barrier();
    }

#undef STAGE_UNIT
#undef LOAD_A
#undef LOAD_B
#undef BARRIER_A
#undef MFMA_PHASE

    // epilogue: acc[mf][ni] -> C[m0 + wr*128 + mf*16 + quad*4 + r][n0 + wc*64 + ni*16 + l16]
    const int row0 = m0 + wr * 128 + quad * 4;
    const int col0 = n0 + wc * 64 + l16;
#pragma unroll
    for (int mf = 0; mf < 8; mf++) {
#pragma unroll
        for (int r = 0; r < 4; r++) {
            size_t rowb = (size_t)(row0 + mf * 16 + r) * N;
#pragma unroll
            for (int ni = 0; ni < 4; ni++) {
                float v = acc[mf][ni][r];
                if (OUT_BF16) ((u16*)Cout)[rowb + col0 + ni * 16] = f2b(v);
                else          ((float*)Cout)[rowb + col0 + ni * 16] = v;
            }
        }
    }
}

// ---------------------------------------------------------------------------
// RoPE(q,k): qkv[B,T,3,H,Dh] -> Q,K (roped) in [B,H,T,Dh]. block per (b,t).
// ---------------------------------------------------------------------------
__global__ __launch_bounds__(256) void rope_qk(const u16* __restrict__ qkv,
                                               u16* __restrict__ Q,
                                               u16* __restrict__ K) {
    const int bt = blockIdx.x;          // 0..4095
    const int b = bt >> 11, t = bt & 2047;
    const u16* row = qkv + (size_t)bt * 6144;
    const int tid = threadIdx.x;

#pragma unroll
    for (int it = 0; it < 8; it++) {
        int p   = it * 256 + tid;
        int qk  = p >> 10;          // 0=q, 1=k (uniform per it)
        int rem = p & 1023;
        int h   = rem >> 6;
        int i   = rem & 63;
        float x1 = b2f(row[qk * 2048 + h * 128 + i]);
        float x2 = b2f(row[qk * 2048 + h * 128 + i + 64]);
        float inv = expf(-0.14391156f * (float)i);   // 10000^(-i/64)
        float th  = (float)t * inv;
        float s, c;
        sincosf(th, &s, &c);
        float o1 = x1 * c - x2 * s;
        float o2 = x2 * c + x1 * s;
        u16* dst = (qk ? K : Q) + ((size_t)((b * 16 + h) * 2048 + t)) * 128;
        dst[i]      = f2b(o1);
        dst[i + 64] = f2b(o2);
    }
}

// ---------------------------------------------------------------------------
// V transpose: qkv[B,T,3,H,Dh] (v slice) -> VT[B,H,Dh,T]. grid (32 tc, 32 bh).
// ---------------------------------------------------------------------------
__global__ __launch_bounds__(256) void vtrans(const u16* __restrict__ qkv,
                                              u16* __restrict__ VT) {
    __shared__ u16 S[64 * 136];         // [t][d], stride 136
    const int tc = blockIdx.x;
    const int bh = blockIdx.y;
    const int b = bh >> 4, h = bh & 15;
    const int tid = threadIdx.x;

#pragma unroll
    for (int i = 0; i < 4; i++) {
        int idx = i * 256 + tid;
        int t  = idx >> 4;
        int d8 = (idx & 15) * 8;
        uint4 v = *(const uint4*)(qkv + ((size_t)(b * 2048 + tc * 64 + t)) * 6144
                                      + 4096 + h * 128 + d8);
        *(uint4*)&S[t * 136 + d8] = v;
    }
    __syncthreads();
#pragma unroll
    for (int i = 0; i < 4; i++) {
        int idx = i * 256 + tid;
        int d  = idx >> 3;
        int t8 = (idx & 7) * 8;
        u16 tmp[8];
#pragma unroll
        for (int j = 0; j < 8; j++) tmp[j] = S[(t8 + j) * 136 + d];
        *(uint4*)(VT + ((size_t)(bh * 128 + d)) * 2048 + tc * 64 + t8) = *(uint4*)tmp;
    }
}

// ---------------------------------------------------------------------------
// causal flash attention v4: v3 + XOR-swizzled K/V LDS tiles.
// grid (16 pairs, 32 bh), 256 thr. Block = 64 q-rows; wave = 16 q-rows.
// ---------------------------------------------------------------------------
__global__ __launch_bounds__(256) void attn(const u16* __restrict__ Q,
                                            const u16* __restrict__ Kg,
                                            const u16* __restrict__ VTg,
                                            u16* __restrict__ O) {
    __shared__ u16 Kl[2][64 * 128];     // [buf][key][d], swizzled
    __shared__ u16 Vt[2][128 * 64];     // [buf][d][key], swizzled
    __shared__ u16 Pl[4 * 16 * 76];     // per-wave P[q][key], stride 76

    const int tid  = threadIdx.x;
    const int w    = tid >> 6;
    const int lane = tid & 63;
    const int quad = lane >> 4;
    const int l16  = lane & 15;
    const int pair = blockIdx.x;        // 0..15
    const int bh   = blockIdx.y;        // 0..31
    const int b = bh >> 4, h = bh & 15;
    const size_t base = (size_t)bh * 2048 * 128;
    const u16* Qb  = Q + base;
    const u16* Kb  = Kg + base;
    const u16* VTb = VTg + base;        // [128 d][2048 t]
    u16* Plw = Pl + w * 16 * 76;
    const float scale = 0.08838834764831845f;   // 1/sqrt(128)

    const int krow = tid >> 4;
    const int kcol = (((tid & 15) ^ (krow & 7)) * 8);
    const int vrow = w * 8 + (lane >> 3);
    const int vcol = (((lane & 7) ^ (vrow & 7)) * 8);
    const int fx   = (l16 & 7);

    for (int s = 0; s < 2; s++) {
        const int qt   = s ? (31 - pair) : pair;
        const int q0   = qt * 64;
        const int row0 = q0 + w * 16;

        bf16x8 Qf[4];
#pragma unroll
        for (int kk = 0; kk < 4; kk++)
            Qf[kk] = *(const bf16x8*)&Qb[(size_t)(row0 + l16) * 128 + kk * 32 + quad * 8];

        f32x4 Oacc[8];
#pragma unroll
        for (int ni = 0; ni < 8; ni++) Oacc[ni] = (f32x4){0.f, 0.f, 0.f, 0.f};
        float mrow = -1e30f, lrow = 0.f;

        const int nkt = qt + 1;

        __syncthreads();
        {
            const u16* ksrc = Kb + (size_t)krow * 128 + kcol;
            char* kdst = (char*)Kl[0] + w * 1024;
            const u16* vsrc = VTb + (size_t)vrow * 2048 + vcol;
            char* vdst = (char*)Vt[0] + w * 1024;
#pragma unroll
            for (int i = 0; i < 4; i++) {
                gload_lds16(ksrc + (size_t)i * 16 * 128, kdst + i * 4096);
                gload_lds16(vsrc + (size_t)i * 32 * 2048, vdst + i * 4096);
            }
        }

        for (int kt = 0; kt < nkt; kt++) {
            const int kt0 = kt * 64;
            const int cur = kt & 1;
            __syncthreads();

            if (kt + 1 < nkt) {
                const int kt1 = kt0 + 64;
                const u16* ksrc = Kb + (size_t)(kt1 + krow) * 128 + kcol;
                char* kdst = (char*)Kl[cur ^ 1] + w * 1024;
                const u16* vsrc = VTb + (size_t)vrow * 2048 + kt1 + vcol;
                char* vdst = (char*)Vt[cur ^ 1] + w * 1024;
#pragma unroll
                for (int i = 0; i < 4; i++) {
                    gload_lds16(ksrc + (size_t)i * 16 * 128, kdst + i * 4096);
                    gload_lds16(vsrc + (size_t)i * 32 * 2048, vdst + i * 4096);
                }
            }

            const u16* Klc = Kl[cur];
            const u16* Vtc = Vt[cur];

            f32x4 ST[4];
#pragma unroll
            for (int mi = 0; mi < 4; mi++) ST[mi] = (f32x4){0.f, 0.f, 0.f, 0.f};
#pragma unroll
            for (int kk = 0; kk < 4; kk++) {
                const int cb = ((kk * 4 + quad) ^ fx) * 8;
#pragma unroll
                for (int mi = 0; mi < 4; mi++) {
                    bf16x8 Kf = *(const bf16x8*)&Klc[(mi * 16 + l16) * 128 + cb];
                    ST[mi] = MFMA_16x16x32_BF16(Kf, Qf[kk], ST[mi]);
                }
            }

            const bool needs_mask = (kt0 + 63) > row0;
            const int qg = row0 + l16;
            float tmax = -1e30f;
#pragma unroll
            for (int mi = 0; mi < 4; mi++) {
#pragma unroll
                for (int r = 0; r < 4; r++) {
                    float sv = ST[mi][r] * scale;
                    if (needs_mask) {
                        int kg = kt0 + mi * 16 + quad * 4 + r;
                        sv = (kg > qg) ? -1e30f : sv;
                    }
                    ST[mi][r] = sv;
                    tmax = fmaxf(tmax, sv);
                }
            }
            tmax = fmaxf(tmax, __shfl_xor(tmax, 16));
            tmax = fmaxf(tmax, __shfl_xor(tmax, 32));

            float mnew  = fmaxf(mrow, tmax);
            float alpha = __expf(mrow - mnew);
            mrow = mnew;

            float tsum = 0.f;
#pragma unroll
            for (int mi = 0; mi < 4; mi++) {
#pragma unroll
                for (int r = 0; r < 4; r++) {
                    float p = __expf(ST[mi][r] - mnew);
                    ST[mi][r] = p;
                    tsum += p;
                }
            }
            lrow = lrow * alpha + tsum;

#pragma unroll
            for (int mi = 0; mi < 4; mi++) {
                ushort4 pk;
                pk.x = f2b(ST[mi][0]); pk.y = f2b(ST[mi][1]);
                pk.z = f2b(ST[mi][2]); pk.w = f2b(ST[mi][3]);
                *(ushort4*)&Plw[l16 * 76 + mi * 16 + quad * 4] = pk;
            }

            float aRow[4];
#pragma unroll
            for (int r = 0; r < 4; r++) aRow[r] = __shfl(alpha, quad * 4 + r);
#pragma unroll
            for (int ni = 0; ni < 8; ni++) {
#pragma unroll
                for (int r = 0; r < 4; r++) Oacc[ni][r] *= aRow[r];
            }

            bf16x8 Pf[2];
#pragma unroll
            for (int kk = 0; kk < 2; kk++)
                Pf[kk] = *(const bf16x8*)&Plw[l16 * 76 + kk * 32 + quad * 8];
#pragma unroll
            for (int kk = 0; kk < 2; kk++) {
                const int cb = ((kk * 4 + quad) ^ fx) * 8;
#pragma unroll
                for (int ni = 0; ni < 8; ni++) {
                    bf16x8 Vf = *(const bf16x8*)&Vtc[(ni * 16 + l16) * 64 + cb];
                    Oacc[ni] = MFMA_16x16x32_BF16(Pf[kk], Vf, Oacc[ni]);
                }
            }
        }

        lrow += __shfl_xor(lrow, 16);
        lrow += __shfl_xor(lrow, 32);
        float inv = 1.0f / lrow;
        float iRow[4];
#pragma unroll
        for (int r = 0; r < 4; r++) iRow[r] = __shfl(inv, quad * 4 + r);

#pragma unroll
        for (int r = 0; r < 4; r++) {
            int t = row0 + quad * 4 + r;
            size_t rowb = ((size_t)(b * 2048 + t)) * 2048 + (size_t)(h * 128);
#pragma unroll
            for (int ni = 0; ni < 8; ni++)
                O[rowb + ni * 16 + l16] = f2b(Oacc[ni][r] * iRow[r]);
        }
    }
}

// ---------------------------------------------------------------------------
extern "C" void kernel_launch(void* const* d_in, const int* in_sizes, int n_in,
                              void* d_out, int out_size, void* d_ws, size_t ws_size,
                              hipStream_t stream) {
    const float* x  = (const float*)d_in[0];
    const float* wq = (const float*)d_in[1];
    const float* wp = (const float*)d_in[2];

    char* ws = (char*)d_ws;
    u16* xb   = (u16*)(ws + 0);            // 16,777,216
    u16* wqb  = (u16*)(ws + 16777216);     // 25,165,824
    u16* wpb  = (u16*)(ws + 41943040);     //  8,388,608
    u16* qkvb = (u16*)(ws + 50331648);     // 50,331,648
    u16* Qr   = (u16*)(ws + 100663296);    // 16,777,216
    u16* Kr   = (u16*)(ws + 117440512);    // 16,777,216
    u16* VTt  = (u16*)(ws + 134217728);    // 16,777,216 (V^T, [B,H,Dh,T])
    u16* Ob   = (u16*)(ws + 50331648);     // overlays qkvb (free after rope/vtrans)
    if (ws_size < 150994944) return;

    // one-time: allow 128 KiB dynamic LDS for gemm256; fall back if refused
    static int use256 = -1;
    if (use256 < 0) {
        hipError_t e = hipFuncSetAttribute(
            reinterpret_cast<const void*>(&gemm256<1>),
            hipFuncAttributeMaxDynamicSharedMemorySize, 131072);
        use256 = (e == hipSuccess) ? 1 : 0;
    }

    cast3<<<2048, 256, 0, stream>>>(x, wq, wp, xb, wqb, wpb);
    if (use256) {
        // grid 384 = (6144/256) x (4096/256); %8==0 for XCD swizzle
        gemm256<1><<<384, 512, 131072, stream>>>(xb, wqb, qkvb, 6144, 2048, 24);
    } else {
        gemm_bt<1><<<dim3(48, 32), 256, 0, stream>>>(xb, wqb, qkvb, 4096, 6144, 2048);
    }
    rope_qk<<<4096, 256, 0, stream>>>(qkvb, Qr, Kr);
    vtrans<<<dim3(32, 32), 256, 0, stream>>>(qkvb, VTt);
    attn<<<dim3(16, 32), 256, 0, stream>>>(Qr, Kr, VTt, Ob);
    gemm_bt<0><<<dim3(16, 32), 256, 0, stream>>>(Ob, wpb, (float*)d_out, 4096, 2048, 2048);
}

// Round 5
// 407.223 us; speedup vs baseline: 1.0344x; 1.0255x over previous
//
#include <hip/hip_runtime.h>
#include <stdint.h>

typedef unsigned short u16;
typedef unsigned int   u32;
typedef __attribute__((ext_vector_type(8))) __bf16 bf16x8;
typedef __attribute__((ext_vector_type(4))) float  f32x4;

#define MFMA_16x16x32_BF16(a, b, c) __builtin_amdgcn_mfma_f32_16x16x32_bf16((a), (b), (c), 0, 0, 0)

__device__ __forceinline__ u16 f2b(float f) {
    u32 u = __builtin_bit_cast(u32, f);
    u32 r = (u + 0x7FFFu + ((u >> 16) & 1u)) >> 16;
    return (u16)r;
}
__device__ __forceinline__ float b2f(u16 h) {
    u32 u = ((u32)h) << 16;
    return __builtin_bit_cast(float, u);
}

// async 16B/lane global->LDS; LDS destination is wave-uniform base + lane*16
__device__ __forceinline__ void gload_lds16(const void* g, void* l) {
    __builtin_amdgcn_global_load_lds(
        (const __attribute__((address_space(1))) u32*)g,
        (__attribute__((address_space(3))) u32*)l,
        16, 0, 0);
}

// ---------------------------------------------------------------------------
// Stage 1: fp32 -> bf16 casts for x, w_qkv, w_proj (grid-stride, float4 lanes)
// ---------------------------------------------------------------------------
__global__ __launch_bounds__(256) void cast3(const float* __restrict__ x,
                                             const float* __restrict__ wq,
                                             const float* __restrict__ wp,
                                             u16* __restrict__ xb,
                                             u16* __restrict__ wqb,
                                             u16* __restrict__ wpb) {
    const int n1 = 8388608, n2 = 12582912, n3 = 4194304;
    const int total4 = (n1 + n2 + n3) / 4;
    for (int i = blockIdx.x * blockDim.x + threadIdx.x; i < total4;
         i += gridDim.x * blockDim.x) {
        int e = i * 4;
        const float* src; u16* dst; int off;
        if (e < n1)            { src = x;  dst = xb;  off = e; }
        else if (e < n1 + n2)  { src = wq; dst = wqb; off = e - n1; }
        else                   { src = wp; dst = wpb; off = e - n1 - n2; }
        float4 v = *(const float4*)(src + off);
        ushort4 o;
        o.x = f2b(v.x); o.y = f2b(v.y); o.z = f2b(v.z); o.w = f2b(v.w);
        *(ushort4*)(dst + off) = o;
    }
}

// ---------------------------------------------------------------------------
// Stage 2/6: C[M,N] = A[M,K] * Bt[N,K]^T (bf16 in, fp32 acc), 128x128 tile,
// BK=64, 256 threads, XOR-swizzled LDS (16B block (row,c) stored at c^(row&7)).
// Keeper structure: 873 TF here; the 256^2 4-phase ports (rounds 1-2) both
// landed at 717 TF because with 2 waves/SIMD the LDS drain and MFMA pipe
// serialize regardless of phase ordering. That line is closed.
// ---------------------------------------------------------------------------
template <int OUT_BF16>
__global__ __launch_bounds__(256) void gemm_bt(const u16* __restrict__ A,
                                               const u16* __restrict__ Bt,
                                               void* __restrict__ Cout,
                                               int M, int N, int K) {
    __shared__ u16 Al[128 * 64];
    __shared__ u16 Bl[128 * 64];
    const int tid  = threadIdx.x;
    const int w    = tid >> 6;
    const int lane = tid & 63;
    const int quad = lane >> 4;
    const int l16  = lane & 15;
    const int m0 = blockIdx.y * 128;
    const int n0 = blockIdx.x * 128;
    const int wm = (w >> 1) * 64;
    const int wn = (w & 1) * 64;

    f32x4 acc[4][4];
#pragma unroll
    for (int i = 0; i < 4; i++) {
#pragma unroll
        for (int j = 0; j < 4; j++) acc[i][j] = (f32x4){0.f, 0.f, 0.f, 0.f};
    }

    const int srow = tid >> 3;
    const int scol = ((tid & 7) ^ (srow & 7)) * 8;
    const u16* Abase = A + (size_t)(m0 + srow) * K + scol;
    const u16* Bbase = Bt + (size_t)(n0 + srow) * K + scol;
    char* AlB = (char*)Al + w * 1024;
    char* BlB = (char*)Bl + w * 1024;
    const int fx = (l16 & 7);

    for (int k0 = 0; k0 < K; k0 += 64) {
        __syncthreads();
#pragma unroll
        for (int i = 0; i < 4; i++) {
            gload_lds16(Abase + (size_t)i * 32 * K + k0, AlB + i * 4096);
            gload_lds16(Bbase + (size_t)i * 32 * K + k0, BlB + i * 4096);
        }
        __syncthreads();
#pragma unroll
        for (int ks = 0; ks < 2; ks++) {
            const int cb = ((ks * 4 + quad) ^ fx) * 8;
            bf16x8 Af[4];
#pragma unroll
            for (int mi = 0; mi < 4; mi++)
                Af[mi] = *(const bf16x8*)&Al[(wm + mi * 16 + l16) * 64 + cb];
#pragma unroll
            for (int ni = 0; ni < 4; ni++) {
                bf16x8 Bf = *(const bf16x8*)&Bl[(wn + ni * 16 + l16) * 64 + cb];
#pragma unroll
                for (int mi = 0; mi < 4; mi++)
                    acc[mi][ni] = MFMA_16x16x32_BF16(Af[mi], Bf, acc[mi][ni]);
            }
        }
    }

    const int row0 = m0 + wm + quad * 4;
    const int col0 = n0 + wn + l16;
#pragma unroll
    for (int mi = 0; mi < 4; mi++) {
#pragma unroll
        for (int r = 0; r < 4; r++) {
            size_t rowb = (size_t)(row0 + mi * 16 + r) * N;
#pragma unroll
            for (int ni = 0; ni < 4; ni++) {
                float v = acc[mi][ni][r];
                if (OUT_BF16) ((u16*)Cout)[rowb + col0 + ni * 16] = f2b(v);
                else          ((float*)Cout)[rowb + col0 + ni * 16] = v;
            }
        }
    }
}

// ---------------------------------------------------------------------------
// Stage 3: RoPE on q,k: qkv[B,T,3,H,Dh] -> roped Q,K in [B,H,T,Dh] layout
// ---------------------------------------------------------------------------
__global__ __launch_bounds__(256) void rope_qk(const u16* __restrict__ qkv,
                                               u16* __restrict__ Q,
                                               u16* __restrict__ K) {
    const int bt = blockIdx.x;          // 0..4095
    const int b = bt >> 11, t = bt & 2047;
    const u16* row = qkv + (size_t)bt * 6144;
    const int tid = threadIdx.x;

#pragma unroll
    for (int it = 0; it < 8; it++) {
        int p   = it * 256 + tid;
        int qk  = p >> 10;          // 0=q, 1=k (wave-uniform per it)
        int rem = p & 1023;
        int h   = rem >> 6;
        int i   = rem & 63;
        float x1 = b2f(row[qk * 2048 + h * 128 + i]);
        float x2 = b2f(row[qk * 2048 + h * 128 + i + 64]);
        float inv = __expf(-0.14391156f * (float)i);   // = 10000^(-i/64)
        float th  = (float)t * inv;
        float s, c;
        sincosf(th, &s, &c);
        float o1 = x1 * c - x2 * s;
        float o2 = x2 * c + x1 * s;
        u16* dst = (qk ? K : Q) + ((size_t)((b * 16 + h) * 2048 + t)) * 128;
        dst[i]      = f2b(o1);
        dst[i + 64] = f2b(o2);
    }
}

// ---------------------------------------------------------------------------
// Stage 4: V transpose: qkv v-slice -> VT[B,H,Dh,T]; grid (32 tc, 32 bh)
// ---------------------------------------------------------------------------
__global__ __launch_bounds__(256) void vtrans(const u16* __restrict__ qkv,
                                              u16* __restrict__ VT) {
    __shared__ u16 S[64 * 136];         // [t][d], padded stride 136
    const int tc = blockIdx.x;
    const int bh = blockIdx.y;
    const int b = bh >> 4, h = bh & 15;
    const int tid = threadIdx.x;

#pragma unroll
    for (int i = 0; i < 4; i++) {
        int idx = i * 256 + tid;
        int t  = idx >> 4;
        int d8 = (idx & 15) * 8;
        uint4 v = *(const uint4*)(qkv + ((size_t)(b * 2048 + tc * 64 + t)) * 6144
                                      + 4096 + h * 128 + d8);
        *(uint4*)&S[t * 136 + d8] = v;
    }
    __syncthreads();
#pragma unroll
    for (int i = 0; i < 4; i++) {
        int idx = i * 256 + tid;
        int d  = idx >> 3;
        int t8 = (idx & 7) * 8;
        u16 tmp[8];
#pragma unroll
        for (int j = 0; j < 8; j++) tmp[j] = S[(t8 + j) * 136 + d];
        *(uint4*)(VT + ((size_t)(bh * 128 + d)) * 2048 + tc * 64 + t8) = *(uint4*)tmp;
    }
}

// ---------------------------------------------------------------------------
// Stage 5: causal flash attention v5 (v4 + T13 defer-max).
// grid (16 pairs, 32 bh), 256 thr; block = 64 q-rows, wave = 16 q-rows.
// ---------------------------------------------------------------------------
__global__ __launch_bounds__(256) void attn(const u16* __restrict__ Q,
                                            const u16* __restrict__ Kg,
                                            const u16* __restrict__ VTg,
                                            u16* __restrict__ O) {
    __shared__ u16 Kl[2][64 * 128];     // [buf][key][d], XOR-swizzled
    __shared__ u16 Vt[2][128 * 64];     // [buf][d][key], XOR-swizzled
    __shared__ u16 Pl[4 * 16 * 76];     // per-wave P[q][key], stride 76

    const int tid  = threadIdx.x;
    const int w    = tid >> 6;
    const int lane = tid & 63;
    const int quad = lane >> 4;
    const int l16  = lane & 15;
    const int pair = blockIdx.x;        // 0..15
    const int bh   = blockIdx.y;        // 0..31
    const int b = bh >> 4, h = bh & 15;
    const size_t base = (size_t)bh * 2048 * 128;
    const u16* Qb  = Q + base;
    const u16* Kb  = Kg + base;
    const u16* VTb = VTg + base;        // [128 d][2048 t]
    u16* Plw = Pl + w * 16 * 76;
    const float scale = 0.08838834764831845f;   // 1/sqrt(128)

    // staging with XOR swizzle: LDS pos (row, p) holds global (row, p^(row&7))
    const int krow = tid >> 4;
    const int kcol = (((tid & 15) ^ (krow & 7)) * 8);
    const int vrow = w * 8 + (lane >> 3);
    const int vcol = (((lane & 7) ^ (vrow & 7)) * 8);
    const int fx   = (l16 & 7);

    for (int s = 0; s < 2; s++) {
        const int qt   = s ? (31 - pair) : pair;
        const int q0   = qt * 64;
        const int row0 = q0 + w * 16;

        // Q fragment (serves as the B operand of the S^T MFMA)
        bf16x8 Qf[4];
#pragma unroll
        for (int kk = 0; kk < 4; kk++)
            Qf[kk] = *(const bf16x8*)&Qb[(size_t)(row0 + l16) * 128 + kk * 32 + quad * 8];

        f32x4 Oacc[8];
#pragma unroll
        for (int ni = 0; ni < 8; ni++) Oacc[ni] = (f32x4){0.f, 0.f, 0.f, 0.f};
        float mrow = -1e30f, lrow = 0.f;    // per-lane softmax state (q = row0+l16)

        const int nkt = qt + 1;

        __syncthreads();    // protect buf0 from the previous s-iteration
        {
            const u16* ksrc = Kb + (size_t)krow * 128 + kcol;
            char* kdst = (char*)Kl[0] + w * 1024;
            const u16* vsrc = VTb + (size_t)vrow * 2048 + vcol;
            char* vdst = (char*)Vt[0] + w * 1024;
#pragma unroll
            for (int i = 0; i < 4; i++) {
                gload_lds16(ksrc + (size_t)i * 16 * 128, kdst + i * 4096);
                gload_lds16(vsrc + (size_t)i * 32 * 2048, vdst + i * 4096);
            }
        }

        for (int kt = 0; kt < nkt; kt++) {
            const int kt0 = kt * 64;
            const int cur = kt & 1;
            __syncthreads();    // drains async loads + syncs block

            if (kt + 1 < nkt) {
                const int kt1 = kt0 + 64;
                const u16* ksrc = Kb + (size_t)(kt1 + krow) * 128 + kcol;
                char* kdst = (char*)Kl[cur ^ 1] + w * 1024;
                const u16* vsrc = VTb + (size_t)vrow * 2048 + kt1 + vcol;
                char* vdst = (char*)Vt[cur ^ 1] + w * 1024;
#pragma unroll
                for (int i = 0; i < 4; i++) {
                    gload_lds16(ksrc + (size_t)i * 16 * 128, kdst + i * 4096);
                    gload_lds16(vsrc + (size_t)i * 32 * 2048, vdst + i * 4096);
                }
            }

            const u16* Klc = Kl[cur];
            const u16* Vtc = Vt[cur];

            // S^T = K Q^T: D[key][q] with q = l16, key = mi*16 + quad*4 + r
            f32x4 ST[4];
#pragma unroll
            for (int mi = 0; mi < 4; mi++) ST[mi] = (f32x4){0.f, 0.f, 0.f, 0.f};
#pragma unroll
            for (int kk = 0; kk < 4; kk++) {
                const int cb = ((kk * 4 + quad) ^ fx) * 8;
#pragma unroll
                for (int mi = 0; mi < 4; mi++) {
                    bf16x8 Kf = *(const bf16x8*)&Klc[(mi * 16 + l16) * 128 + cb];
                    ST[mi] = MFMA_16x16x32_BF16(Kf, Qf[kk], ST[mi]);
                }
            }

            // scale + causal mask (diagonal tiles only)
            const bool needs_mask = (kt0 + 63) > row0;
            const int qg = row0 + l16;
            float tmax = -1e30f;
#pragma unroll
            for (int mi = 0; mi < 4; mi++) {
#pragma unroll
                for (int r = 0; r < 4; r++) {
                    float sv = ST[mi][r] * scale;
                    if (needs_mask) {
                        int kg = kt0 + mi * 16 + quad * 4 + r;
                        sv = (kg > qg) ? -1e30f : sv;
                    }
                    ST[mi][r] = sv;
                    tmax = fmaxf(tmax, sv);
                }
            }
            tmax = fmaxf(tmax, __shfl_xor(tmax, 16));
            tmax = fmaxf(tmax, __shfl_xor(tmax, 32));
            // tmax is identical across quads per l16, so mrow evolves uniformly

            // T13 defer-max: only rescale O when some row's max grew by > 8.
            // Otherwise keep m_old; P = exp(S - m_old) <= e^8, safe in fp32/bf16,
            // and the final 1/lrow normalization absorbs the scaling.
            if (__any(tmax > mrow + 8.0f)) {
                float mnew  = fmaxf(mrow, tmax);
                float alpha = __expf(mrow - mnew);
                mrow = mnew;
                lrow *= alpha;
                float aRow[4];
#pragma unroll
                for (int r = 0; r < 4; r++) aRow[r] = __shfl(alpha, quad * 4 + r);
#pragma unroll
                for (int ni = 0; ni < 8; ni++) {
#pragma unroll
                    for (int r = 0; r < 4; r++) Oacc[ni][r] *= aRow[r];
                }
            }

            float tsum = 0.f;
#pragma unroll
            for (int mi = 0; mi < 4; mi++) {
#pragma unroll
                for (int r = 0; r < 4; r++) {
                    float p = __expf(ST[mi][r] - mrow);
                    ST[mi][r] = p;
                    tsum += p;
                }
            }
            lrow += tsum;

            // P[q][key] -> LDS (b64 packs, padded stride 76)
#pragma unroll
            for (int mi = 0; mi < 4; mi++) {
                ushort4 pk;
                pk.x = f2b(ST[mi][0]); pk.y = f2b(ST[mi][1]);
                pk.z = f2b(ST[mi][2]); pk.w = f2b(ST[mi][3]);
                *(ushort4*)&Plw[l16 * 76 + mi * 16 + quad * 4] = pk;
            }

            // O += P V
            bf16x8 Pf[2];
#pragma unroll
            for (int kk = 0; kk < 2; kk++)
                Pf[kk] = *(const bf16x8*)&Plw[l16 * 76 + kk * 32 + quad * 8];
#pragma unroll
            for (int kk = 0; kk < 2; kk++) {
                const int cb = ((kk * 4 + quad) ^ fx) * 8;
#pragma unroll
                for (int ni = 0; ni < 8; ni++) {
                    bf16x8 Vf = *(const bf16x8*)&Vtc[(ni * 16 + l16) * 64 + cb];
                    Oacc[ni] = MFMA_16x16x32_BF16(Pf[kk], Vf, Oacc[ni]);
                }
            }
        }

        // final normalization: reduce per-lane partials across quads
        lrow += __shfl_xor(lrow, 16);
        lrow += __shfl_xor(lrow, 32);
        float inv = 1.0f / lrow;
        float iRow[4];
#pragma unroll
        for (int r = 0; r < 4; r++) iRow[r] = __shfl(inv, quad * 4 + r);

#pragma unroll
        for (int r = 0; r < 4; r++) {
            int t = row0 + quad * 4 + r;
            size_t rowb = ((size_t)(b * 2048 + t)) * 2048 + (size_t)(h * 128);
#pragma unroll
            for (int ni = 0; ni < 8; ni++)
                O[rowb + ni * 16 + l16] = f2b(Oacc[ni][r] * iRow[r]);
        }
    }
}

// ---------------------------------------------------------------------------
extern "C" void kernel_launch(void* const* d_in, const int* in_sizes, int n_in,
                              void* d_out, int out_size, void* d_ws, size_t ws_size,
                              hipStream_t stream) {
    const float* x  = (const float*)d_in[0];
    const float* wq = (const float*)d_in[1];
    const float* wp = (const float*)d_in[2];

    char* ws = (char*)d_ws;
    u16* xb   = (u16*)(ws + 0);            // 16,777,216 B
    u16* wqb  = (u16*)(ws + 16777216);     // 25,165,824 B
    u16* wpb  = (u16*)(ws + 41943040);     //  8,388,608 B
    u16* qkvb = (u16*)(ws + 50331648);     // 50,331,648 B
    u16* Qr   = (u16*)(ws + 100663296);    // 16,777,216 B
    u16* Kr   = (u16*)(ws + 117440512);    // 16,777,216 B
    u16* VTt  = (u16*)(ws + 134217728);    // 16,777,216 B (V^T, [B,H,Dh,T])
    u16* Ob   = (u16*)(ws + 50331648);     // overlays qkvb (dead after rope/vtrans)
    if (ws_size < 150994944) return;

    cast3<<<2048, 256, 0, stream>>>(x, wq, wp, xb, wqb, wpb);
    gemm_bt<1><<<dim3(48, 32), 256, 0, stream>>>(xb, wqb, qkvb, 4096, 6144, 2048);
    rope_qk<<<4096, 256, 0, stream>>>(qkvb, Qr, Kr);
    vtrans<<<dim3(32, 32), 256, 0, stream>>>(qkvb, VTt);
    attn<<<dim3(16, 32), 256, 0, stream>>>(Qr, Kr, VTt, Ob);
    gemm_bt<0><<<dim3(16, 32), 256, 0, stream>>>(Ob, wpb, (float*)d_out, 4096, 2048, 2048);
}